// Round 3
// baseline (182.159 us; speedup 1.0000x reference)
//
#include <hip/hip_runtime.h>

// y:   (B=32, K=64, n1=4, n2=8, n3=8) fp32
// W1d: (K,1,256,1,1) -> w1[k][i]
// W2d: (K,1,1,4,4)   -> w2[k][j][l]
// out[b, x*256+i, yy*4+j, z*4+l] = sum_k y[b,k,x,yy,z] * w1[k,i] * w2[k,j,l]
//
// GEMM view per (b,x,yy): out[i,c] = sum_k w1[k,i] * s[k,c],
// c = j*32 + z*4 + l in [0,128), s[k,c] = y[k,z]*w2[k,j,l] built in regs.
//
// LDS is DELIVERY-bandwidth bound (128 B/clk/CU, broadcasts pay full cost), so
// maximize FMAs per LDS byte: 16i x 8c register tile -> 88 B delivered per
// 128 FMAs per lane per k (vs 52 B / 32 FMAs in the previous version).
//
// Block: 128 threads (2 waves) = 16 tx (c0=tx*8) x 8 ty (i0=ty*16),
// covers 128 i x 128 c. w1 staged in two 32-k chunks (16 KiB); LDS total 22 KiB.

#define KC 32

__global__ __launch_bounds__(128, 2)
void backproj_kernel(const float* __restrict__ y,
                     const float* __restrict__ w1,
                     const float* __restrict__ w2,
                     float* __restrict__ out)
{
    __shared__ float  y_s[64 * 8];      //  2 KiB : y[k][z]
    __shared__ float4 w2_s[64 * 4];     //  4 KiB : w2[k][j]
    __shared__ float4 w1c[KC * 32];     // 16 KiB : [kk][i4], i in [0,128) of this half

    const int bid   = blockIdx.x;
    const int ihalf = bid & 1;
    const int yy    = (bid >> 1) & 7;
    const int x     = (bid >> 4) & 3;
    const int b     = bid >> 6;

    const int tid = threadIdx.x;   // 0..127
    const int tx  = tid & 15;      // c0 = tx*8
    const int ty  = tid >> 4;      // i0 = ty*16
    const int j   = tx >> 2;       // c0 = j*32 + z0*4
    const int z0  = (tx & 3) * 2;  // two z per thread: z0, z0+1

    // ---- stage y slice (512 floats) and w2 (1024 floats) once
    {
        const float* ybase = y + (size_t)b * 16384 + x * 64 + yy * 8;
        int k = tid >> 1, h = tid & 1;
        ((float4*)y_s)[tid] = ((const float4*)(ybase + k * 256))[h];
        w2_s[tid]       = ((const float4*)w2)[tid];
        w2_s[tid + 128] = ((const float4*)w2)[tid + 128];
    }

    float4 acc[16][2];
    #pragma unroll
    for (int r = 0; r < 16; ++r) {
        acc[r][0] = make_float4(0.f, 0.f, 0.f, 0.f);
        acc[r][1] = make_float4(0.f, 0.f, 0.f, 0.f);
    }

    const float* w1base = w1 + ihalf * 128;

    for (int kb = 0; kb < 64; kb += KC) {
        __syncthreads();   // w1c reuse guard (and y_s/w2_s readiness on pass 0)
        // ---- stage w1 chunk: [kb..kb+KC) x 128 i = 1024 float4
        #pragma unroll
        for (int p = 0; p < 8; ++p) {
            int idx = p * 128 + tid;
            int kk = idx >> 5, q = idx & 31;
            w1c[idx] = ((const float4*)(w1base + (kb + kk) * 256))[q];
        }
        __syncthreads();

        #pragma unroll 2
        for (int kk = 0; kk < KC; ++kk) {
            const int k = kb + kk;
            const float2 yv  = *(const float2*)&y_s[k * 8 + z0];   // b64, 4 addrs/wave
            const float4 w2v = w2_s[k * 4 + j];                    // b128, 4 addrs/wave
            float4 sv0, sv1;
            sv0.x = yv.x * w2v.x; sv0.y = yv.x * w2v.y; sv0.z = yv.x * w2v.z; sv0.w = yv.x * w2v.w;
            sv1.x = yv.y * w2v.x; sv1.y = yv.y * w2v.y; sv1.z = yv.y * w2v.z; sv1.w = yv.y * w2v.w;

            const float4* wrow = &w1c[kk * 32 + ty * 4];           // 4x b128, 4 addrs/wave

#define FMA_ROW(r, wc)                                                              \
            acc[r][0].x += (wc) * sv0.x; acc[r][0].y += (wc) * sv0.y;               \
            acc[r][0].z += (wc) * sv0.z; acc[r][0].w += (wc) * sv0.w;               \
            acc[r][1].x += (wc) * sv1.x; acc[r][1].y += (wc) * sv1.y;               \
            acc[r][1].z += (wc) * sv1.z; acc[r][1].w += (wc) * sv1.w;

            #pragma unroll
            for (int q = 0; q < 4; ++q) {
                const float4 wv = wrow[q];
                FMA_ROW(q * 4 + 0, wv.x)
                FMA_ROW(q * 4 + 1, wv.y)
                FMA_ROW(q * 4 + 2, wv.z)
                FMA_ROW(q * 4 + 3, wv.w)
            }
#undef FMA_ROW
        }
    }

    // ---- store: 16 rows x 8 floats (2x dwordx4 each), wave-contiguous in c
    float* obase = out
        + (size_t)(b * 1024 + x * 256 + ihalf * 128 + ty * 16) * 1024
        + yy * 128 + tx * 8;
    #pragma unroll
    for (int r = 0; r < 16; ++r) {
        *(float4*)(obase + r * 1024)     = acc[r][0];
        *(float4*)(obase + r * 1024 + 4) = acc[r][1];
    }
}

extern "C" void kernel_launch(void* const* d_in, const int* in_sizes, int n_in,
                              void* d_out, int out_size, void* d_ws, size_t ws_size,
                              hipStream_t stream) {
    const float* y  = (const float*)d_in[0];
    const float* w1 = (const float*)d_in[1];   // (64, 256)
    const float* w2 = (const float*)d_in[2];   // (64, 16)
    float* out = (float*)d_out;

    // grid = 32 b x 4 x x 8 yy x 2 ihalf = 2048 blocks of 128 threads
    backproj_kernel<<<dim3(2048), dim3(128), 0, stream>>>(y, w1, w2, out);
}

// Round 5
// 152.270 us; speedup vs baseline: 1.1963x; 1.1963x over previous
//
#include <hip/hip_runtime.h>

// y:   (B=32, K=64, n1=4, n2=8, n3=8) fp32
// W1d: (K,1,256,1,1) -> w1[k][i]
// W2d: (K,1,1,4,4)   -> w2[k][j][l]
// out[b, x*256+i, yy*4+j, z*4+l] = sum_k y[b,k,x,yy,z] * w1[k,i] * w2[k,j,l]
//
// MFMA formulation (validated at absmax 0.25 in round 4's first launch):
//   per (b,x,yy): out[i,c] = sum_k w1[k,i] * s[k,c],
//   c = j*32 + z*4 + l in [0,128), s[k,c] = y[k,z]*w2[k,j,l], bf16 in / fp32 acc.
// Threshold 1.13; exact fp32 scores 0.125; bf16 rounding lands ~0.25.
//
// Round-5 change vs round 4: NO w1T LDS staging — A-fragments are loaded
// directly from global w1 (64 KiB, L2-hot) and converted in registers.
// Only one LDS-producer phase remains (y_s, then sT), each barrier-guarded.
//
// mfma_f32_16x16x32_bf16 layouts (m89/m91-verified):
//   A: lane holds A[m=lane&15][k=(lane>>4)*8 + j], j=0..7
//   B: lane holds B[k=(lane>>4)*8 + j][n=lane&15]
//   D: col=lane&15, row=(lane>>4)*4 + reg
// sT stored [c][k], k-stride padded to 72 ushorts (144 B): b128 frag reads are
// 16B-aligned, lanes la and la+8 alias exactly -> 2-way (free, m136).

typedef __bf16 bf16x8 __attribute__((ext_vector_type(8)));
typedef float  f32x4  __attribute__((ext_vector_type(4)));

#define LDK 72  // padded k-stride in ushorts

__device__ __forceinline__ unsigned short f2bf(float f) {
    union { float f; unsigned u; } v; v.f = f;
    unsigned r = v.u + 0x7fffu + ((v.u >> 16) & 1u);   // round-to-nearest-even
    return (unsigned short)(r >> 16);
}
__device__ __forceinline__ unsigned pack2(float a, float b) {
    return (unsigned)f2bf(a) | ((unsigned)f2bf(b) << 16);
}

__global__ __launch_bounds__(256)
void backproj_kernel(const float* __restrict__ y,
                     const float* __restrict__ w1,
                     const float* __restrict__ w2,
                     float* __restrict__ out)
{
    __shared__ float y_s[64 * 8];                          //  2 KiB : y[k][z]
    __shared__ __align__(16) unsigned short sT[128 * LDK]; // 18 KiB : [c][k] bf16

    const int bid = blockIdx.x;
    const int iq  = bid & 3;
    const int yy  = (bid >> 2) & 7;
    const int x   = (bid >> 5) & 3;
    const int b   = bid >> 7;

    const int tid  = threadIdx.x;
    const int wave = tid >> 6, lane = tid & 63;
    const int la   = lane & 15, quad = lane >> 4;

    // ---- phase A: stage y slice (512 floats, coalesced float4)
    if (tid < 128) {
        const float* ybase = y + (size_t)b * 16384 + x * 64 + yy * 8;
        int k = tid >> 1, h = tid & 1;
        ((float4*)y_s)[tid] = ((const float4*)(ybase + k * 256))[h];
    }

    // ---- A-fragments straight from global (w1 is L2-hot), overlap with y stage.
    // a0: k = quad*8 + j (j=0..7); a1: k = 32 + quad*8 + j.  i = iq*64+wave*16+la.
    bf16x8 a0, a1;
    {
        const float* wcol = w1 + iq * 64 + wave * 16 + la;
        union { unsigned u[4]; bf16x8 v; } ua, ub;
        #pragma unroll
        for (int j = 0; j < 8; j += 2) {
            float f0 = wcol[(quad * 8 + j) * 256];
            float f1 = wcol[(quad * 8 + j + 1) * 256];
            float g0 = wcol[(32 + quad * 8 + j) * 256];
            float g1 = wcol[(32 + quad * 8 + j + 1) * 256];
            ua.u[j >> 1] = pack2(f0, f1);
            ub.u[j >> 1] = pack2(g0, g1);
        }
        a0 = ua.v; a1 = ub.v;
    }

    __syncthreads();   // y_s ready

    // ---- phase B: build sT[c][k] = bf16(y[k,z] * w2[k,j,l]); 2 threads per c.
    {
        const int c  = tid >> 1;             // 0..127
        const int kh = (tid & 1) * 32;       // k-half
        const int j = c >> 5, z = (c >> 2) & 7, l = c & 3;
        const float* w2p = w2 + j * 4 + l;
        unsigned* dst = (unsigned*)&sT[c * LDK + kh];
        #pragma unroll
        for (int kk = 0; kk < 32; kk += 2) {
            float f0 = y_s[(kh + kk) * 8 + z]     * w2p[(kh + kk) * 16];
            float f1 = y_s[(kh + kk + 1) * 8 + z] * w2p[(kh + kk + 1) * 16];
            dst[kk >> 1] = pack2(f0, f1);
        }
    }
    __syncthreads();   // sT ready

    // ---- compute: per wave, 1 i-tile x 8 c-tiles, K=64 (2 MFMAs per c-tile)
    f32x4 acc[8];
    #pragma unroll
    for (int mt = 0; mt < 8; ++mt) acc[mt] = (f32x4){0.f, 0.f, 0.f, 0.f};

    #pragma unroll
    for (int mt = 0; mt < 8; ++mt) {
        const bf16x8 b0 = *(const bf16x8*)&sT[(mt * 16 + la) * LDK + quad * 8];
        const bf16x8 b1 = *(const bf16x8*)&sT[(mt * 16 + la) * LDK + 32 + quad * 8];
        acc[mt] = __builtin_amdgcn_mfma_f32_16x16x32_bf16(a0, b0, acc[mt], 0, 0, 0);
        acc[mt] = __builtin_amdgcn_mfma_f32_16x16x32_bf16(a1, b1, acc[mt], 0, 0, 0);
    }

    // ---- epilogue: D row=(quad*4+reg) -> i, col=la -> c (validated round 4)
    const int i_row0 = iq * 64 + wave * 16 + quad * 4;
    float* op = out + ((size_t)(b * 1024 + x * 256 + i_row0)) * 1024 + yy * 128 + la;
    #pragma unroll
    for (int mt = 0; mt < 8; ++mt) {
        float* o = op + mt * 16;
        o[0]    = acc[mt][0];
        o[1024] = acc[mt][1];
        o[2048] = acc[mt][2];
        o[3072] = acc[mt][3];
    }
}

extern "C" void kernel_launch(void* const* d_in, const int* in_sizes, int n_in,
                              void* d_out, int out_size, void* d_ws, size_t ws_size,
                              hipStream_t stream) {
    const float* y  = (const float*)d_in[0];
    const float* w1 = (const float*)d_in[1];   // (64, 256)
    const float* w2 = (const float*)d_in[2];   // (64, 16)
    float* out = (float*)d_out;

    // grid = 32 b x 4 x x 8 yy x 4 iq = 4096 blocks of 256 threads
    backproj_kernel<<<dim3(4096), dim3(256), 0, stream>>>(y, w1, w2, out);
}